// Round 5
// baseline (558.479 us; speedup 1.0000x reference)
//
#include <hip/hip_runtime.h>
#include <stdint.h>

#define M_DIM 16384
#define N_DIM 4096
#define K_DIM 4096

#define BM 256
#define BN 256
#define BK 128
#define NT (K_DIM / BK)  // 32 K-tiles

typedef int i32x4 __attribute__((ext_vector_type(4)));

// ---- async global->LDS 16B (dest = wave-uniform base, HW adds lane*16) ----
__device__ __forceinline__ void async16(const uint8_t* g, uint8_t* l) {
    __builtin_amdgcn_global_load_lds(
        (const __attribute__((address_space(1))) void*)g,
        (__attribute__((address_space(3))) void*)l,
        16, 0, 0);
}

// ---------------- weight pack: int32 -> int8 ----------------
__global__ __launch_bounds__(256) void pack_w_kernel(const int* __restrict__ w32,
                                                     uint32_t* __restrict__ w8,
                                                     int n4) {
    int i = blockIdx.x * 256 + threadIdx.x;
    if (i < n4) {
        const int4 v = reinterpret_cast<const int4*>(w32)[i];
        uint32_t p = (uint32_t)(v.x & 255) | ((uint32_t)(v.y & 255) << 8) |
                     ((uint32_t)(v.z & 255) << 16) | ((uint32_t)(v.w & 255) << 24);
        w8[i] = p;
    }
}

// ---------------- per-row dynamic activation quant ----------------
__global__ __launch_bounds__(256) void quant_kernel(const float* __restrict__ x,
                                                    uint32_t* __restrict__ xq,
                                                    float* __restrict__ xscale) {
    const int m = blockIdx.x;
    const int t = threadIdx.x;
    const float4* row = reinterpret_cast<const float4*>(x + (size_t)m * K_DIM);
    float4 v[4];
    float amax = 0.0f;
#pragma unroll
    for (int i = 0; i < 4; ++i) {
        v[i] = row[t + i * 256];
        amax = fmaxf(amax, fmaxf(fmaxf(fabsf(v[i].x), fabsf(v[i].y)),
                                 fmaxf(fabsf(v[i].z), fabsf(v[i].w))));
    }
#pragma unroll
    for (int off = 32; off > 0; off >>= 1) amax = fmaxf(amax, __shfl_xor(amax, off));
    __shared__ float smax[4];
    if ((t & 63) == 0) smax[t >> 6] = amax;
    __syncthreads();
    amax = fmaxf(fmaxf(smax[0], smax[1]), fmaxf(smax[2], smax[3]));
    const float scale = amax / 127.0f;
    const float s = fmaxf(scale, 1e-8f);
    if (t == 0) xscale[m] = scale;
    uint32_t* orow = xq + (size_t)m * (K_DIM / 4);
#pragma unroll
    for (int i = 0; i < 4; ++i) {
        int q0 = __float2int_rn(v[i].x / s);
        int q1 = __float2int_rn(v[i].y / s);
        int q2 = __float2int_rn(v[i].z / s);
        int q3 = __float2int_rn(v[i].w / s);
        q0 = max(-127, min(127, q0));
        q1 = max(-127, min(127, q1));
        q2 = max(-127, min(127, q2));
        q3 = max(-127, min(127, q3));
        uint32_t p = (uint32_t)(q0 & 255) | ((uint32_t)(q1 & 255) << 8) |
                     ((uint32_t)(q2 & 255) << 16) | ((uint32_t)(q3 & 255) << 24);
        orow[t + i * 256] = p;
    }
}

// ---------------- int8 GEMM, 256x256, cross-phase pipelined ----------------
// 512 threads = 8 waves (2M x 4N), per-wave output 128x64, 16x16x64 MFMA
// (proven 0-conflict fragment pattern). K-tile BK=128 = 2 kk-halves of 64.
// LDS: 2 x (A 32KB + B 32KB) = 128KB.
// Steady state per tile t (ONE barrier, TWO lgkm, ONE vmcnt):
//   lgkm(0)                ; kk0(t) frags ready (issued last tile, drained
//                            under last tile's kk1 MFMA cluster)
//   stage(t+1) x8 -> other buf
//   read kk1(t) x12        ; drains under cluster kk0
//   MFMA kk0(t) x32
//   lgkm(0)                ; kk1 ready
//   vmcnt(0)               ; own stage(t+1) landed
//   BAR                    ; all stages landed; all buf(t) reads done
//   read kk0(t+1) x12      ; drains under cluster kk1 (regs kk0 free)
//   MFMA kk1(t) x32
// Swizzle: LDS(row r, unit p) holds global unit p^(r&7) (pre-swizzled source,
// linear LDS dest, XOR on ds_read). Verified 0 bank conflicts in r1-r3.
__global__ __launch_bounds__(512, 2) void gemm_kernel(
    const uint8_t* __restrict__ Aq, const float* __restrict__ ascale,
    const uint8_t* __restrict__ Bq, const float* __restrict__ wscale,
    float* __restrict__ out) {
    __shared__ uint8_t lds[2 * BM * BK + 2 * BN * BK];
    uint8_t* ldsA0 = lds;
    uint8_t* ldsA1 = lds + BM * BK;
    uint8_t* ldsB0 = lds + 2 * BM * BK;
    uint8_t* ldsB1 = lds + 2 * BM * BK + BN * BK;

    const int tid = threadIdx.x;
    const int lane = tid & 63;
    const int w = tid >> 6;
    const int wr = w >> 2;     // 0..1 -> M offset wr*128
    const int wc = w & 3;      // 0..3 -> N offset wc*64
    const int lr = lane & 15;  // row within 16x16 fragment
    const int lg = lane >> 4;  // k-group 0..3 (16B each)
    const int aa = lane >> 3;  // staging: row-within-8
    const int pp = lane & 7;   // staging: unit-within-row

    // XCD-aware bijective swizzle (1024 blocks, 1024%8==0)
    const int bid = blockIdx.x;
    const int swz = (bid & 7) * (1024 / 8) + (bid >> 3);
    const size_t row0 = (size_t)(swz >> 4) * BM;  // 64 M-tiles
    const size_t col0 = (size_t)(swz & 15) * BN;  // 16 N-tiles
    const uint8_t* Ab = Aq + row0 * K_DIM;
    const uint8_t* Bb = Bq + col0 * K_DIM;

    i32x4 acc[8][4];
#pragma unroll
    for (int i = 0; i < 8; ++i)
#pragma unroll
        for (int j = 0; j < 4; ++j) acc[i][j] = (i32x4){0, 0, 0, 0};

#define STAGE_A(DST, KT, MH)                                                     \
    do {                                                                         \
        _Pragma("unroll") for (int it_ = 0; it_ < 2; ++it_) {                    \
            const int m_ = (MH) * 64 + w * 8 + aa + it_ * 128;                   \
            async16(Ab + (size_t)m_ * K_DIM + (KT) * BK + ((pp ^ aa) << 4),      \
                    (DST) + ((MH) * 64 + w * 8 + it_ * 128) * BK);               \
        }                                                                        \
    } while (0)

#define STAGE_B(DST, KT, NH)                                                     \
    do {                                                                         \
        _Pragma("unroll") for (int it_ = 0; it_ < 2; ++it_) {                    \
            const int rwh_ = it_ * 64 + w * 8 + aa;                              \
            const int n_ = (NH) * 32 + (rwh_ & 31) + ((rwh_ >> 5) << 6);         \
            const int rw0_ = it_ * 64 + w * 8;                                   \
            const int nb_ = (NH) * 32 + (rw0_ & 31) + ((rw0_ >> 5) << 6);        \
            async16(Bb + (size_t)n_ * K_DIM + (KT) * BK + ((pp ^ aa) << 4),      \
                    (DST) + nb_ * BK);                                           \
        }                                                                        \
    } while (0)

#define STAGE_TILE(LA, LB, KT)   \
    do {                         \
        STAGE_A(LA, KT, 0);      \
        STAGE_A(LA, KT, 1);      \
        STAGE_B(LB, KT, 0);      \
        STAGE_B(LB, KT, 1);      \
    } while (0)

    // kk-half reads: A 8 frags (q = MH*4+mf), B 4 frags (p = NH*2+nf)
#define READ_AK(BUF, KK)                                                         \
    do {                                                                         \
        _Pragma("unroll") for (int q_ = 0; q_ < 8; ++q_) {                       \
            const int r_ = wr * 128 + q_ * 16 + lr;                              \
            const int u_ = (KK) * 4 + lg;                                        \
            afk[KK][q_] = *reinterpret_cast<const i32x4*>(                       \
                (BUF) + r_ * BK + ((u_ ^ (r_ & 7)) << 4));                       \
        }                                                                        \
    } while (0)

#define READ_BK(BUF, KK)                                                         \
    do {                                                                         \
        _Pragma("unroll") for (int p_ = 0; p_ < 4; ++p_) {                       \
            const int r_ = wc * 64 + p_ * 16 + lr;                               \
            const int u_ = (KK) * 4 + lg;                                        \
            bfk[KK][p_] = *reinterpret_cast<const i32x4*>(                       \
                (BUF) + r_ * BK + ((u_ ^ (r_ & 7)) << 4));                       \
        }                                                                        \
    } while (0)

#define CLUSTER(KK)                                                              \
    do {                                                                         \
        __builtin_amdgcn_s_setprio(1);                                           \
        _Pragma("unroll") for (int q_ = 0; q_ < 8; ++q_)                         \
        _Pragma("unroll") for (int p_ = 0; p_ < 4; ++p_)                         \
            acc[q_][p_] = __builtin_amdgcn_mfma_i32_16x16x64_i8(                 \
                afk[KK][q_], bfk[KK][p_], acc[q_][p_], 0, 0, 0);                 \
        __builtin_amdgcn_s_setprio(0);                                           \
    } while (0)

#define BAR __builtin_amdgcn_s_barrier()
#define SB0 __builtin_amdgcn_sched_barrier(0)
#define VMCNT0 asm volatile("s_waitcnt vmcnt(0)" ::: "memory")
#define LGKM0                                              \
    do {                                                   \
        asm volatile("s_waitcnt lgkmcnt(0)" ::: "memory"); \
        __builtin_amdgcn_sched_barrier(0);                 \
    } while (0)

    i32x4 afk[2][8], bfk[2][4];

    // ---- prologue: stage tile0, wait, first kk0 reads ----
    STAGE_TILE(ldsA0, ldsB0, 0);
    VMCNT0;
    BAR;
    READ_AK(ldsA0, 0);
    READ_BK(ldsB0, 0);

#pragma unroll 1
    for (int it2 = 0; it2 < NT / 2; ++it2) {
        const int t = 2 * it2;
        const int tn2 = (t + 2 < NT) ? t + 2 : NT - 1;  // clamped tail (dead data)

        // ======== tile t (buf0) ========
        LGKM0;                        // kk0(t) ready (drained under prev cluster)
        STAGE_TILE(ldsA1, ldsB1, t + 1);
        READ_AK(ldsA0, 1);            // kk1(t): drains under cluster kk0
        READ_BK(ldsB0, 1);
        CLUSTER(0);
        LGKM0;                        // kk1(t) ready
        VMCNT0;                       // own stage(t+1) landed
        BAR;                          // all stages landed; all buf0 reads done
        READ_AK(ldsA1, 0);            // kk0(t+1): drains under cluster kk1
        READ_BK(ldsB1, 0);
        CLUSTER(1);

        // ======== tile t+1 (buf1) ========
        LGKM0;                        // kk0(t+1) ready
        STAGE_TILE(ldsA0, ldsB0, tn2);
        READ_AK(ldsA1, 1);            // kk1(t+1)
        READ_BK(ldsB1, 1);
        CLUSTER(0);
        LGKM0;
        VMCNT0;
        BAR;
        READ_AK(ldsA0, 0);            // kk0(t+2) (dead reads at final iter)
        READ_BK(ldsB0, 0);
        CLUSTER(1);
    }

    // ---- epilogue: C/D layout col = lane&15, row = (lane>>4)*4 + reg ----
    const float* asp = ascale + row0 + wr * 128;
    const float* wsp = wscale + col0 + wc * 64;
    float wsv[4];
#pragma unroll
    for (int nf = 0; nf < 4; ++nf) wsv[nf] = wsp[nf * 16 + lr];
    float* outBase = out + (row0 + wr * 128) * (size_t)N_DIM + col0 + wc * 64;
#pragma unroll
    for (int mf = 0; mf < 8; ++mf) {
#pragma unroll
        for (int j = 0; j < 4; ++j) {
            const int r = mf * 16 + lg * 4 + j;
            const float av = asp[r];
            float* orow = outBase + (size_t)r * N_DIM;
#pragma unroll
            for (int nf = 0; nf < 4; ++nf) {
                orow[nf * 16 + lr] = (float)acc[mf][nf][j] * av * wsv[nf];
            }
        }
    }
#undef STAGE_A
#undef STAGE_B
#undef STAGE_TILE
#undef READ_AK
#undef READ_BK
#undef CLUSTER
#undef BAR
#undef SB0
#undef VMCNT0
#undef LGKM0
}

extern "C" void kernel_launch(void* const* d_in, const int* in_sizes, int n_in,
                              void* d_out, int out_size, void* d_ws, size_t ws_size,
                              hipStream_t stream) {
    const float* x = (const float*)d_in[0];
    const int* w32 = (const int*)d_in[1];
    const float* wscale = (const float*)d_in[2];
    float* out = (float*)d_out;

    uint8_t* ws = (uint8_t*)d_ws;
    uint32_t* xq = (uint32_t*)ws;                                  // 64 MiB
    float* xscale = (float*)(ws + (size_t)M_DIM * K_DIM);          // 64 KiB
    uint8_t* wq = ws + (size_t)M_DIM * K_DIM + (size_t)M_DIM * 4;  // 16 MiB

    pack_w_kernel<<<dim3((N_DIM * K_DIM / 4 + 255) / 256), 256, 0, stream>>>(
        w32, (uint32_t*)wq, N_DIM * K_DIM / 4);
    quant_kernel<<<dim3(M_DIM), 256, 0, stream>>>(x, xq, xscale);
    gemm_kernel<<<dim3((M_DIM / BM) * (N_DIM / BN)), 512, 0, stream>>>(
        (const uint8_t*)xq, xscale, wq, wscale, out);
}